// Round 1
// baseline (15.010 us; speedup 1.0000x reference)
//
#include <hip/hip_runtime.h>
#include <math.h>

namespace {

constexpr int B_ = 128;
constexpr int T_ = 4096;
constexpr int U_ = 128;
constexpr int F_ = 32;
constexpr int K_ = 31;
constexpr int WIN_ = 7;
constexpr int SLICES = 4;
constexpr int SLICE_W = T_ / SLICES;   // 1024 elements per slice-block
constexpr int NTHREADS = 256;

// One block per (slice, batch-row). Every block (re)computes the tiny
// 7-position window softmax (so no cross-block dependencies), then writes
// its 1024-column slice of alignments and next_state. Slice 0 writes argmax.
__global__ __launch_bounds__(NTHREADS) void lsa_kernel(
    const float* __restrict__ query,    // B*U
    const float* __restrict__ state,    // B*T
    const float* __restrict__ memory,   // B*T*U
    const float* __restrict__ conv_w,   // K*1*F
    const float* __restrict__ conv_b,   // F
    const float* __restrict__ loc_w,    // F*U
    const float* __restrict__ v_a,      // U
    const float* __restrict__ b_a,      // U
    const int*   __restrict__ prev,     // B
    float* __restrict__ out_align,      // B*T
    float* __restrict__ out_state,      // B*T
    float* __restrict__ out_maxattn)    // B (stored as float)
{
    const int b     = blockIdx.y;
    const int slice = blockIdx.x;
    const int tid   = threadIdx.x;

    const int pm = prev[b];
    const int lo = max(0, pm - 4);
    const int hi = min(T_ - 1, pm + 2);
    const int w  = hi - lo + 1;        // <= 7, always >= 1 (window contains pm)

    __shared__ float s_loc[WIN_][F_];  // conv features at window positions
    __shared__ float s_energy[WIN_];
    __shared__ float s_align[WIN_];
    __shared__ float s_red[4];
    __shared__ int   s_amax;

    // ---- 1) loc_feat[j][f] = conv_b[f] + sum_k state[b, lo+j+k-15]*conv_w[k,0,f]
    if (tid < w * F_) {
        const int j = tid / F_;
        const int f = tid % F_;
        const int t = lo + j;
        float acc = conv_b[f];
        #pragma unroll
        for (int k = 0; k < K_; ++k) {
            const int src = t + k - (K_ / 2);
            const float sv = (src >= 0 && src < T_) ? state[(size_t)b * T_ + src] : 0.f;
            acc += sv * conv_w[k * F_ + f];
        }
        s_loc[j][f] = acc;
    }
    __syncthreads();

    // ---- 2) energy[j] = sum_u v_a[u]*tanh(memory[b,t,u] + query[b,u] + proc_loc + b_a[u])
    // threads 0..127 handle window position j0, threads 128..255 handle j0+1
    const int u    = tid & (U_ - 1);
    const int grp  = tid >> 7;         // 0 or 1
    const int wave = tid >> 6;         // 0..3
    const float q  = query[b * U_ + u];
    const float va = v_a[u];
    const float ba = b_a[u];

    for (int j0 = 0; j0 < WIN_; j0 += 2) {
        const int j = j0 + grp;
        float e = 0.f;
        if (j < w) {
            float pl = 0.f;
            #pragma unroll
            for (int f = 0; f < F_; ++f)
                pl += s_loc[j][f] * loc_w[f * U_ + u];
            const int t = lo + j;
            const float m = memory[((size_t)b * T_ + t) * U_ + u];
            e = va * tanhf(m + q + pl + ba);
        }
        // reduce 128 lanes (2 waves) per group
        #pragma unroll
        for (int off = 32; off > 0; off >>= 1)
            e += __shfl_down(e, off);
        if ((tid & 63) == 0) s_red[wave] = e;
        __syncthreads();
        if (tid == 0   && j0 < w)     s_energy[j0]     = s_red[0] + s_red[1];
        if (tid == 128 && j0 + 1 < w) s_energy[j0 + 1] = s_red[2] + s_red[3];
        __syncthreads();               // protect s_red reuse next iteration
    }

    // ---- 3) softmax over the window + first-occurrence argmax
    if (tid == 0) {
        float mx = s_energy[0];
        for (int j = 1; j < w; ++j) mx = fmaxf(mx, s_energy[j]);
        float a[WIN_];
        float sum = 0.f;
        for (int j = 0; j < w; ++j) { a[j] = expf(s_energy[j] - mx); sum += a[j]; }
        for (int j = 0; j < w; ++j) { a[j] = a[j] / sum; s_align[j] = a[j]; }
        float best = -1.f; int bj = 0;
        for (int j = 0; j < w; ++j)
            if (a[j] > best) { best = a[j]; bj = j; }
        s_amax = lo + bj;
    }
    __syncthreads();

    // ---- 4) stream this block's slice: alignments (0 outside window) and
    //          next_state = state + alignments
    const size_t row  = (size_t)b * T_;
    const int    base = slice * SLICE_W;
    const float4* st4 = reinterpret_cast<const float4*>(state + row + base);
    float4* oa4 = reinterpret_cast<float4*>(out_align + row + base);
    float4* os4 = reinterpret_cast<float4*>(out_state + row + base);

    {
        const int i  = tid;                 // SLICE_W/4 == NTHREADS
        const int t0 = base + i * 4;
        const float4 sv = st4[i];
        float4 av;
        av.x = (t0 + 0 >= lo && t0 + 0 <= hi) ? s_align[t0 + 0 - lo] : 0.f;
        av.y = (t0 + 1 >= lo && t0 + 1 <= hi) ? s_align[t0 + 1 - lo] : 0.f;
        av.z = (t0 + 2 >= lo && t0 + 2 <= hi) ? s_align[t0 + 2 - lo] : 0.f;
        av.w = (t0 + 3 >= lo && t0 + 3 <= hi) ? s_align[t0 + 3 - lo] : 0.f;
        float4 ns;
        ns.x = sv.x + av.x;
        ns.y = sv.y + av.y;
        ns.z = sv.z + av.z;
        ns.w = sv.w + av.w;
        oa4[i] = av;
        os4[i] = ns;
    }

    if (slice == 0 && tid == 0)
        out_maxattn[b] = (float)s_amax;
}

} // namespace

extern "C" void kernel_launch(void* const* d_in, const int* in_sizes, int n_in,
                              void* d_out, int out_size, void* d_ws, size_t ws_size,
                              hipStream_t stream) {
    const float* query  = (const float*)d_in[0];
    const float* state  = (const float*)d_in[1];
    const float* memory = (const float*)d_in[2];
    const float* conv_w = (const float*)d_in[3];
    const float* conv_b = (const float*)d_in[4];
    const float* loc_w  = (const float*)d_in[5];
    const float* v_a    = (const float*)d_in[6];
    const float* b_a    = (const float*)d_in[7];
    const int*   prev   = (const int*)d_in[8];

    float* out = (float*)d_out;
    float* out_align   = out;                       // B*T
    float* out_state   = out + (size_t)B_ * T_;     // B*T
    float* out_maxattn = out + (size_t)2 * B_ * T_; // B

    dim3 grid(SLICES, B_);
    lsa_kernel<<<grid, NTHREADS, 0, stream>>>(
        query, state, memory, conv_w, conv_b, loc_w, v_a, b_a, prev,
        out_align, out_state, out_maxattn);
}

// Round 2
// 13.326 us; speedup vs baseline: 1.1264x; 1.1264x over previous
//
#include <hip/hip_runtime.h>
#include <math.h>

namespace {

constexpr int B_ = 128;
constexpr int T_ = 4096;
constexpr int U_ = 128;
constexpr int F_ = 32;
constexpr int K_ = 31;
constexpr int WIN_ = 7;
constexpr int SLICES = 4;
constexpr int SLICE_W = T_ / SLICES;   // 1024 columns per slice-block
constexpr int NTHREADS = 256;

// One block per (slice, batch-row). Blocks whose slice intersects the 7-wide
// attention window (or contains pm) compute the window softmax; all blocks
// stream their 1024-column slice of alignments and next_state.
__global__ __launch_bounds__(NTHREADS) void lsa_kernel(
    const float* __restrict__ query,    // B*U
    const float* __restrict__ state,    // B*T
    const float* __restrict__ memory,   // B*T*U
    const float* __restrict__ conv_w,   // K*1*F
    const float* __restrict__ conv_b,   // F
    const float* __restrict__ loc_w,    // F*U
    const float* __restrict__ v_a,      // U
    const float* __restrict__ b_a,      // U
    const int*   __restrict__ prev,     // B
    float* __restrict__ out_align,      // B*T
    float* __restrict__ out_state,      // B*T
    float* __restrict__ out_maxattn)    // B (stored as float)
{
    const int b     = blockIdx.y;
    const int slice = blockIdx.x;
    const int tid   = threadIdx.x;
    const int base  = slice * SLICE_W;

    const int pm = prev[b];
    const int lo = max(0, pm - 4);
    const int hi = min(T_ - 1, pm + 2);
    const int w  = hi - lo + 1;        // 3..7, window always contains pm

    __shared__ float s_loc[WIN_][F_];  // conv features at window positions
    __shared__ float s_energy[WIN_];
    __shared__ float s_align[WIN_];
    __shared__ int   s_amax;

    // ---- issue the streaming state load immediately (independent of all else)
    const size_t row = (size_t)b * T_;
    const float4 sv  = reinterpret_cast<const float4*>(state + row + base)[tid];

    const bool has_pm     = (pm >= base) && (pm < base + SLICE_W);
    const bool has_window = (base <= hi) && (base + SLICE_W > lo);

    if (has_window || has_pm) {
        const int j    = tid >> 5;       // 0..7 (j<7 valid window slots)
        const int lane = tid & 31;       // 32 lanes cover u in float4s

        // ---- issue the memory window load early (independent of conv)
        float4 mv = make_float4(0.f, 0.f, 0.f, 0.f);
        if (j < w) {
            const int t = lo + j;
            mv = reinterpret_cast<const float4*>(memory + (row + t) * U_)[lane];
        }
        const float4 q4  = reinterpret_cast<const float4*>(query + (size_t)b * U_)[lane];
        const float4 va4 = reinterpret_cast<const float4*>(v_a)[lane];
        const float4 ba4 = reinterpret_cast<const float4*>(b_a)[lane];

        // ---- conv features: one thread per (window pos, filter)
        if (tid < w * F_) {
            const int cj = tid / F_;
            const int f  = tid % F_;
            const int t  = lo + cj;
            float acc = conv_b[f];
            #pragma unroll
            for (int k = 0; k < K_; ++k) {
                const int src = t + k - (K_ / 2);
                const float svv = (src >= 0 && src < T_) ? state[row + src] : 0.f;
                acc += svv * conv_w[k * F_ + f];
            }
            s_loc[cj][f] = acc;
        }
        __syncthreads();

        // ---- energy, all 7 positions in one pass
        float e = 0.f;
        if (j < w) {
            float4 pl = make_float4(0.f, 0.f, 0.f, 0.f);
            #pragma unroll
            for (int f = 0; f < F_; ++f) {
                const float lf = s_loc[j][f];
                const float4 lw = reinterpret_cast<const float4*>(loc_w + f * U_)[lane];
                pl.x += lf * lw.x; pl.y += lf * lw.y;
                pl.z += lf * lw.z; pl.w += lf * lw.w;
            }
            e  = va4.x * tanhf(mv.x + q4.x + pl.x + ba4.x);
            e += va4.y * tanhf(mv.y + q4.y + pl.y + ba4.y);
            e += va4.z * tanhf(mv.z + q4.z + pl.z + ba4.z);
            e += va4.w * tanhf(mv.w + q4.w + pl.w + ba4.w);
        }
        // reduce within each 32-lane group (stays inside the 64-lane wave)
        #pragma unroll
        for (int off = 16; off > 0; off >>= 1)
            e += __shfl_xor(e, off);
        if (lane == 0 && j < w) s_energy[j] = e;
        __syncthreads();

        // ---- softmax over the window + first-occurrence argmax
        if (tid == 0) {
            float mx = s_energy[0];
            for (int jj = 1; jj < w; ++jj) mx = fmaxf(mx, s_energy[jj]);
            float a[WIN_];
            float sum = 0.f;
            for (int jj = 0; jj < w; ++jj) { a[jj] = expf(s_energy[jj] - mx); sum += a[jj]; }
            const float inv = 1.f / sum;
            float best = -1.f; int bj = 0;
            for (int jj = 0; jj < w; ++jj) {
                const float av = a[jj] * inv;
                s_align[jj] = av;
                if (av > best) { best = av; bj = jj; }
            }
            s_amax = lo + bj;
        }
        __syncthreads();
    }

    // ---- stream this block's slice: alignments (0 outside window) and
    //      next_state = state + alignments
    {
        const int t0 = base + tid * 4;
        float4 av;
        av.x = (t0 + 0 >= lo && t0 + 0 <= hi) ? s_align[t0 + 0 - lo] : 0.f;
        av.y = (t0 + 1 >= lo && t0 + 1 <= hi) ? s_align[t0 + 1 - lo] : 0.f;
        av.z = (t0 + 2 >= lo && t0 + 2 <= hi) ? s_align[t0 + 2 - lo] : 0.f;
        av.w = (t0 + 3 >= lo && t0 + 3 <= hi) ? s_align[t0 + 3 - lo] : 0.f;
        float4 ns;
        ns.x = sv.x + av.x;
        ns.y = sv.y + av.y;
        ns.z = sv.z + av.z;
        ns.w = sv.w + av.w;
        reinterpret_cast<float4*>(out_align + row + base)[tid] = av;
        reinterpret_cast<float4*>(out_state + row + base)[tid] = ns;
    }

    if (has_pm && tid == 0)
        out_maxattn[b] = (float)s_amax;
}

} // namespace

extern "C" void kernel_launch(void* const* d_in, const int* in_sizes, int n_in,
                              void* d_out, int out_size, void* d_ws, size_t ws_size,
                              hipStream_t stream) {
    const float* query  = (const float*)d_in[0];
    const float* state  = (const float*)d_in[1];
    const float* memory = (const float*)d_in[2];
    const float* conv_w = (const float*)d_in[3];
    const float* conv_b = (const float*)d_in[4];
    const float* loc_w  = (const float*)d_in[5];
    const float* v_a    = (const float*)d_in[6];
    const float* b_a    = (const float*)d_in[7];
    const int*   prev   = (const int*)d_in[8];

    float* out = (float*)d_out;
    float* out_align   = out;                       // B*T
    float* out_state   = out + (size_t)B_ * T_;     // B*T
    float* out_maxattn = out + (size_t)2 * B_ * T_; // B

    dim3 grid(SLICES, B_);
    lsa_kernel<<<grid, NTHREADS, 0, stream>>>(
        query, state, memory, conv_w, conv_b, loc_w, v_a, b_a, prev,
        out_align, out_state, out_maxattn);
}